// Round 1
// baseline (2792.538 us; speedup 1.0000x reference)
//
#include <hip/hip_runtime.h>
#include <cstdint>
#include <cstddef>

#define Dm 512
#define Sm 512
#define Bm 8
#define Hm 8
#define Fm 2048
#define Mm 4096   // B*S
#define Lm 4

typedef __bf16 bf16x8 __attribute__((ext_vector_type(8)));
typedef float  fx4    __attribute__((ext_vector_type(4)));
typedef unsigned short u16;
typedef unsigned short u16x4 __attribute__((ext_vector_type(4)));
typedef short s16x8 __attribute__((ext_vector_type(8)));

__device__ __forceinline__ u16 f2b(float f) {
  union { float f; uint32_t u; } v; v.f = f;
  uint32_t u = v.u;
  return (u16)((u + 0x7fffu + ((u >> 16) & 1u)) >> 16);  // RNE
}
__device__ __forceinline__ float b2f(u16 h) {
  union { uint32_t u; float f; } v; v.u = ((uint32_t)h) << 16;
  return v.f;
}

// ---------------- elementwise ----------------
__global__ void cast_bf16_kernel(const float* __restrict__ in, u16* __restrict__ out) {
  int i = (blockIdx.x * 256 + threadIdx.x) * 4;
  fx4 v = *(const fx4*)(in + i);
  u16x4 o;
  #pragma unroll
  for (int j = 0; j < 4; ++j) o[j] = f2b(v[j]);
  *(u16x4*)(out + i) = o;
}

__global__ void avg3_kernel(const u16* __restrict__ o3, u16* __restrict__ out) {
  int i = (blockIdx.x * 256 + threadIdx.x) * 4;
  u16x4 a = *(const u16x4*)(o3 + i);
  u16x4 b = *(const u16x4*)(o3 + (size_t)Mm*Dm + i);
  u16x4 c = *(const u16x4*)(o3 + (size_t)2*Mm*Dm + i);
  u16x4 r;
  #pragma unroll
  for (int j = 0; j < 4; ++j)
    r[j] = f2b((b2f(a[j]) + b2f(b[j]) + b2f(c[j])) * (1.f/3.f));
  *(u16x4*)(out + i) = r;
}

// ---------------- layernorm (1 wave / row) ----------------
__global__ void ln_kernel(const float* __restrict__ in, const float* __restrict__ gam,
                          const float* __restrict__ bet, float* __restrict__ outf,
                          u16* __restrict__ outb) {
  int row = blockIdx.x;
  int t = threadIdx.x;  // 64
  const float* x = in + (size_t)row * Dm;
  fx4 v0 = *(const fx4*)(x + t*4);
  fx4 v1 = *(const fx4*)(x + 256 + t*4);
  float s = 0.f, sq = 0.f;
  #pragma unroll
  for (int j = 0; j < 4; ++j) { s += v0[j] + v1[j]; sq += v0[j]*v0[j] + v1[j]*v1[j]; }
  #pragma unroll
  for (int off = 1; off < 64; off <<= 1) { s += __shfl_xor(s, off, 64); sq += __shfl_xor(sq, off, 64); }
  float mu  = s * (1.f/Dm);
  float var = sq * (1.f/Dm) - mu*mu;
  float rstd = rsqrtf(var + 1e-6f);
  fx4 g0 = *(const fx4*)(gam + t*4), g1 = *(const fx4*)(gam + 256 + t*4);
  fx4 b0 = *(const fx4*)(bet + t*4), b1 = *(const fx4*)(bet + 256 + t*4);
  float* of = outf + (size_t)row*Dm;
  u16*   ob = outb + (size_t)row*Dm;
  fx4 y0, y1; u16x4 h0, h1;
  #pragma unroll
  for (int j = 0; j < 4; ++j) {
    y0[j] = (v0[j]-mu)*rstd*g0[j] + b0[j];
    y1[j] = (v1[j]-mu)*rstd*g1[j] + b1[j];
    h0[j] = f2b(y0[j]); h1[j] = f2b(y1[j]);
  }
  *(fx4*)(of + t*4) = y0; *(fx4*)(of + 256 + t*4) = y1;
  *(u16x4*)(ob + t*4) = h0; *(u16x4*)(ob + 256 + t*4) = h1;
}

// ---------------- causal-conv GEMM (Q/K/V for all 3 branches), grid.z = 9 ----------------
#define BM 128
#define BN 128
#define BK 32
#define LDT 48   // LDS row stride (bf16 elems); 96 B, keeps 16B alignment, spreads banks

__global__ void conv_gemm_kernel(const u16* __restrict__ xb,
    const float* __restrict__ Wq1, const float* __restrict__ Wq3, const float* __restrict__ Wq5,
    const float* __restrict__ Wk1, const float* __restrict__ Wk3, const float* __restrict__ Wk5,
    const float* __restrict__ Wv,
    const float* __restrict__ bq, const float* __restrict__ bk, const float* __restrict__ bv,
    u16* __restrict__ qb, u16* __restrict__ kb, u16* __restrict__ vb, int layer) {
  __shared__ u16 As[BM][LDT];
  __shared__ u16 Bs[BN][LDT];   // transposed: Bs[n][k]
  int z = blockIdx.z;
  int which = z / 3, br = z - which*3;
  int taps; const float* W; const float* bias; u16* out;
  if (which == 0) {
    taps = (br==0)?1:(br==1)?3:5;
    W = ((br==0)?Wq1:(br==1)?Wq3:Wq5) + (size_t)layer*taps*Dm*Dm;
    bias = bq + (size_t)(layer*3+br)*Dm;
    out = qb + (size_t)br*Mm*Dm;
  } else if (which == 1) {
    taps = (br==0)?1:(br==1)?3:5;
    W = ((br==0)?Wk1:(br==1)?Wk3:Wk5) + (size_t)layer*taps*Dm*Dm;
    bias = bk + (size_t)(layer*3+br)*Dm;
    out = kb + (size_t)br*Mm*Dm;
  } else {
    taps = 1;
    W = Wv + (size_t)(layer*3+br)*Dm*Dm;
    bias = bv + (size_t)(layer*3+br)*Dm;
    out = vb + (size_t)br*Mm*Dm;
  }
  int tid = threadIdx.x;
  int lane = tid & 63, wid = tid >> 6;
  int wm = wid >> 1, wn = wid & 1;
  int r16 = lane & 15, g = lane >> 4;
  int brow = blockIdx.x * BM, bcol = blockIdx.y * BN;

  fx4 acc[4][4] = {};
  for (int t = 0; t < taps; ++t) {
    int shift = taps - 1 - t;
    const float* Wt = W + (size_t)t*Dm*Dm;
    for (int c0 = 0; c0 < Dm; c0 += BK) {
      #pragma unroll
      for (int it = 0; it < 2; ++it) {           // A: 128x32 bf16
        int idx = it*256 + tid;
        int row = idx >> 2, ch = (idx & 3) * 8;
        int grow = brow + row;
        int s = grow & (Sm-1);
        s16x8 v = {};
        if (s - shift >= 0) v = *(const s16x8*)(xb + (size_t)(grow - shift)*Dm + c0 + ch);
        *(s16x8*)(&As[row][ch]) = v;
      }
      #pragma unroll
      for (int it = 0; it < 4; ++it) {           // B: 32x128 fp32 -> bf16 transposed
        int idx = it*256 + tid;
        int kk = idx >> 5, nch = (idx & 31) * 4;
        fx4 w = *(const fx4*)(Wt + (size_t)(c0+kk)*Dm + bcol + nch);
        #pragma unroll
        for (int j = 0; j < 4; ++j) Bs[nch+j][kk] = f2b(w[j]);
      }
      __syncthreads();
      bf16x8 a[4], b[4];
      #pragma unroll
      for (int m = 0; m < 4; ++m) a[m] = *(const bf16x8*)(&As[wm*64 + m*16 + r16][g*8]);
      #pragma unroll
      for (int n = 0; n < 4; ++n) b[n] = *(const bf16x8*)(&Bs[wn*64 + n*16 + r16][g*8]);
      #pragma unroll
      for (int m = 0; m < 4; ++m)
        #pragma unroll
        for (int n = 0; n < 4; ++n)
          acc[m][n] = __builtin_amdgcn_mfma_f32_16x16x32_bf16(a[m], b[n], acc[m][n], 0, 0, 0);
      __syncthreads();
    }
  }
  #pragma unroll
  for (int m = 0; m < 4; ++m) {
    int row = brow + wm*64 + m*16 + g*4;
    #pragma unroll
    for (int n = 0; n < 4; ++n) {
      int col = bcol + wn*64 + n*16 + r16;
      float bv_ = bias[col];
      #pragma unroll
      for (int r = 0; r < 4; ++r)
        out[(size_t)(row + r)*Dm + col] = f2b(acc[m][n][r] + bv_);
    }
  }
}

// ---------------- dense GEMM: MODE 0 = bf16 relu out (FFN1); MODE 1 = f32 out + residual ----------------
template<int MODE>
__global__ void gemm_kernel(const u16* __restrict__ A, const float* __restrict__ W,
                            const float* __restrict__ bias, const float* __restrict__ res,
                            u16* __restrict__ outb, float* __restrict__ outf, int K, int N) {
  __shared__ u16 As[BM][LDT];
  __shared__ u16 Bs[BN][LDT];
  int tid = threadIdx.x;
  int lane = tid & 63, wid = tid >> 6;
  int wm = wid >> 1, wn = wid & 1;
  int r16 = lane & 15, g = lane >> 4;
  int brow = blockIdx.x * BM, bcol = blockIdx.y * BN;
  fx4 acc[4][4] = {};
  for (int c0 = 0; c0 < K; c0 += BK) {
    #pragma unroll
    for (int it = 0; it < 2; ++it) {
      int idx = it*256 + tid;
      int row = idx >> 2, ch = (idx & 3) * 8;
      s16x8 v = *(const s16x8*)(A + (size_t)(brow+row)*K + c0 + ch);
      *(s16x8*)(&As[row][ch]) = v;
    }
    #pragma unroll
    for (int it = 0; it < 4; ++it) {
      int idx = it*256 + tid;
      int kk = idx >> 5, nch = (idx & 31) * 4;
      fx4 w = *(const fx4*)(W + (size_t)(c0+kk)*N + bcol + nch);
      #pragma unroll
      for (int j = 0; j < 4; ++j) Bs[nch+j][kk] = f2b(w[j]);
    }
    __syncthreads();
    bf16x8 a[4], b[4];
    #pragma unroll
    for (int m = 0; m < 4; ++m) a[m] = *(const bf16x8*)(&As[wm*64 + m*16 + r16][g*8]);
    #pragma unroll
    for (int n = 0; n < 4; ++n) b[n] = *(const bf16x8*)(&Bs[wn*64 + n*16 + r16][g*8]);
    #pragma unroll
    for (int m = 0; m < 4; ++m)
      #pragma unroll
      for (int n = 0; n < 4; ++n)
        acc[m][n] = __builtin_amdgcn_mfma_f32_16x16x32_bf16(a[m], b[n], acc[m][n], 0, 0, 0);
    __syncthreads();
  }
  #pragma unroll
  for (int m = 0; m < 4; ++m) {
    int row0 = brow + wm*64 + m*16 + g*4;
    #pragma unroll
    for (int n = 0; n < 4; ++n) {
      int col = bcol + wn*64 + n*16 + r16;
      float bv_ = bias[col];
      #pragma unroll
      for (int r = 0; r < 4; ++r) {
        size_t idx = (size_t)(row0 + r)*N + col;
        float v = acc[m][n][r] + bv_;
        if (MODE == 0) outb[idx] = f2b(fmaxf(v, 0.f));
        else           outf[idx] = v + res[idx];
      }
    }
  }
}

// ---------------- flash attention: grid (qtile 8, b*h 64, branch 3), 256 thr ----------------
__global__ void attn_kernel(const u16* __restrict__ qb, const u16* __restrict__ kb,
                            const u16* __restrict__ vb, u16* __restrict__ ob) {
  __shared__ u16 Ks[64][72];
  __shared__ u16 Vs[64][72];        // transposed: Vs[d][k]
  __shared__ u16 Ps[4][16][72];     // per-wave P tile
  int qt = blockIdx.x, bh = blockIdx.y, br = blockIdx.z;
  int b = bh >> 3, h = bh & 7;
  const u16* q = qb + (size_t)br*Mm*Dm;
  const u16* k = kb + (size_t)br*Mm*Dm;
  const u16* v = vb + (size_t)br*Mm*Dm;
  u16* o = ob + (size_t)br*Mm*Dm;
  int tid = threadIdx.x, lane = tid & 63, wid = tid >> 6;
  int r16 = lane & 15, g = lane >> 4;
  size_t rowbase = (size_t)b * Sm;
  int qrow0 = qt*64 + wid*16;

  bf16x8 qa[2];
  #pragma unroll
  for (int c = 0; c < 2; ++c)
    qa[c] = *(const bf16x8*)(q + (rowbase + qrow0 + r16)*Dm + h*64 + c*32 + g*8);

  float mrow[4], lrow[4];
  fx4 accO[4] = {};
  #pragma unroll
  for (int r = 0; r < 4; ++r) { mrow[r] = -3.0e38f; lrow[r] = 0.f; }

  for (int kt = 0; kt <= qt; ++kt) {
    #pragma unroll
    for (int it = 0; it < 2; ++it) {
      int idx = it*256 + tid;
      int row = idx >> 3, ch = (idx & 7) * 8;
      s16x8 kv = *(const s16x8*)(k + (rowbase + kt*64 + row)*Dm + h*64 + ch);
      *(s16x8*)(&Ks[row][ch]) = kv;
      s16x8 vv = *(const s16x8*)(v + (rowbase + kt*64 + row)*Dm + h*64 + ch);
      #pragma unroll
      for (int j = 0; j < 8; ++j) Vs[ch+j][row] = (u16)vv[j];
    }
    __syncthreads();
    fx4 sacc[4] = {};
    #pragma unroll
    for (int n = 0; n < 4; ++n)
      #pragma unroll
      for (int c = 0; c < 2; ++c) {
        bf16x8 kf = *(const bf16x8*)(&Ks[n*16 + r16][c*32 + g*8]);
        sacc[n] = __builtin_amdgcn_mfma_f32_16x16x32_bf16(qa[c], kf, sacc[n], 0, 0, 0);
      }
    float sv[4][4];
    bool diag = (kt == qt);
    #pragma unroll
    for (int n = 0; n < 4; ++n)
      #pragma unroll
      for (int r = 0; r < 4; ++r) {
        float s = sacc[n][r] * 0.125f;
        if (diag) {
          int col = n*16 + r16;
          int rowq = wid*16 + g*4 + r;
          if (col > rowq) s = -3.0e38f;
        }
        sv[n][r] = s;
      }
    #pragma unroll
    for (int r = 0; r < 4; ++r) {
      float rm = fmaxf(fmaxf(sv[0][r], sv[1][r]), fmaxf(sv[2][r], sv[3][r]));
      #pragma unroll
      for (int off = 1; off < 16; off <<= 1) rm = fmaxf(rm, __shfl_xor(rm, off, 64));
      float mnew = fmaxf(mrow[r], rm);
      float corr = __expf(mrow[r] - mnew);
      mrow[r] = mnew;
      float rs = 0.f;
      #pragma unroll
      for (int n = 0; n < 4; ++n) { float p = __expf(sv[n][r] - mnew); sv[n][r] = p; rs += p; }
      #pragma unroll
      for (int off = 1; off < 16; off <<= 1) rs += __shfl_xor(rs, off, 64);
      lrow[r] = lrow[r]*corr + rs;
      #pragma unroll
      for (int n = 0; n < 4; ++n) accO[n][r] *= corr;
    }
    #pragma unroll
    for (int n = 0; n < 4; ++n)
      #pragma unroll
      for (int r = 0; r < 4; ++r)
        Ps[wid][g*4 + r][n*16 + r16] = f2b(sv[n][r]);
    #pragma unroll
    for (int kk = 0; kk < 2; ++kk) {
      bf16x8 pa = *(const bf16x8*)(&Ps[wid][r16][kk*32 + g*8]);
      #pragma unroll
      for (int n = 0; n < 4; ++n) {
        bf16x8 vf = *(const bf16x8*)(&Vs[n*16 + r16][kk*32 + g*8]);
        accO[n] = __builtin_amdgcn_mfma_f32_16x16x32_bf16(pa, vf, accO[n], 0, 0, 0);
      }
    }
    __syncthreads();
  }
  #pragma unroll
  for (int n = 0; n < 4; ++n)
    #pragma unroll
    for (int r = 0; r < 4; ++r) {
      int qrow = qt*64 + wid*16 + g*4 + r;
      o[(rowbase + qrow)*Dm + h*64 + n*16 + r16] = f2b(accO[n][r] / lrow[r]);
    }
}

// ---------------- host ----------------
extern "C" void kernel_launch(void* const* d_in, const int* in_sizes, int n_in,
                              void* d_out, int out_size, void* d_ws, size_t ws_size,
                              hipStream_t stream) {
  const float* x_in = (const float*)d_in[0];
  const float* Wq1 = (const float*)d_in[1];
  const float* Wk1 = (const float*)d_in[2];
  const float* Wq3 = (const float*)d_in[3];
  const float* Wk3 = (const float*)d_in[4];
  const float* Wq5 = (const float*)d_in[5];
  const float* Wk5 = (const float*)d_in[6];
  const float* bq  = (const float*)d_in[7];
  const float* bk  = (const float*)d_in[8];
  const float* Wv  = (const float*)d_in[9];
  const float* bv  = (const float*)d_in[10];
  const float* Wo  = (const float*)d_in[11];
  const float* bo  = (const float*)d_in[12];
  const float* W1  = (const float*)d_in[13];
  const float* b1  = (const float*)d_in[14];
  const float* W2  = (const float*)d_in[15];
  const float* b2  = (const float*)d_in[16];
  const float* ln1g = (const float*)d_in[17];
  const float* ln1b = (const float*)d_in[18];
  const float* ln2g = (const float*)d_in[19];
  const float* ln2b = (const float*)d_in[20];

  char* ws = (char*)d_ws;
  size_t off = 0;
  auto alloc = [&](size_t bytes) { void* p = ws + off; off += (bytes + 255) & ~(size_t)255; return p; };
  float* x_f32 = (float*)alloc((size_t)Mm*Dm*4);
  u16*   xb    = (u16*)  alloc((size_t)Mm*Dm*2);
  u16*   qbuf  = (u16*)  alloc((size_t)3*Mm*Dm*2);
  u16*   kbuf  = (u16*)  alloc((size_t)3*Mm*Dm*2);
  u16*   vbuf  = (u16*)  alloc((size_t)3*Mm*Dm*2);
  u16*   obuf  = (u16*)  alloc((size_t)3*Mm*Dm*2);
  u16*   avgb  = (u16*)  alloc((size_t)Mm*Dm*2);
  float* pre   = (float*)alloc((size_t)Mm*Dm*4);
  float* out1f = (float*)alloc((size_t)Mm*Dm*4);
  u16*   out1b = (u16*)  alloc((size_t)Mm*Dm*2);
  u16*   midb  = (u16*)  alloc((size_t)Mm*Fm*2);

  cast_bf16_kernel<<<2048, 256, 0, stream>>>(x_in, xb);
  for (int l = 0; l < Lm; ++l) {
    const float* xs = (l == 0) ? x_in : x_f32;
    conv_gemm_kernel<<<dim3(32, 4, 9), 256, 0, stream>>>(
        xb, Wq1, Wq3, Wq5, Wk1, Wk3, Wk5, Wv, bq, bk, bv, qbuf, kbuf, vbuf, l);
    attn_kernel<<<dim3(8, 64, 3), 256, 0, stream>>>(qbuf, kbuf, vbuf, obuf);
    avg3_kernel<<<2048, 256, 0, stream>>>(obuf, avgb);
    gemm_kernel<1><<<dim3(32, 4), 256, 0, stream>>>(
        avgb, Wo + (size_t)l*Dm*Dm, bo + (size_t)l*Dm, xs, nullptr, pre, Dm, Dm);
    ln_kernel<<<4096, 64, 0, stream>>>(pre, ln1g + (size_t)l*Dm, ln1b + (size_t)l*Dm, out1f, out1b);
    gemm_kernel<0><<<dim3(32, 16), 256, 0, stream>>>(
        out1b, W1 + (size_t)l*Dm*Fm, b1 + (size_t)l*Fm, nullptr, midb, nullptr, Dm, Fm);
    gemm_kernel<1><<<dim3(32, 4), 256, 0, stream>>>(
        midb, W2 + (size_t)l*Fm*Dm, b2 + (size_t)l*Dm, out1f, nullptr, pre, Fm, Dm);
    float* lnout = (l == Lm-1) ? (float*)d_out : x_f32;
    ln_kernel<<<4096, 64, 0, stream>>>(pre, ln2g + (size_t)l*Dm, ln2b + (size_t)l*Dm, lnout, xb);
  }
}

// Round 2
// 808.372 us; speedup vs baseline: 3.4545x; 3.4545x over previous
//
#include <hip/hip_runtime.h>
#include <cstdint>
#include <cstddef>

#define Dm 512
#define Sm 512
#define Bm 8
#define Hm 8
#define Fm 2048
#define Mm 4096   // B*S
#define Lm 4

typedef __bf16 bf16x8 __attribute__((ext_vector_type(8)));
typedef float  fx4    __attribute__((ext_vector_type(4)));
typedef unsigned short u16;
typedef unsigned short u16x4 __attribute__((ext_vector_type(4)));
typedef short s16x8 __attribute__((ext_vector_type(8)));

__device__ __forceinline__ u16 f2b(float f) {
  union { float f; uint32_t u; } v; v.f = f;
  uint32_t u = v.u;
  return (u16)((u + 0x7fffu + ((u >> 16) & 1u)) >> 16);  // RNE
}
__device__ __forceinline__ float b2f(u16 h) {
  union { uint32_t u; float f; } v; v.u = ((uint32_t)h) << 16;
  return v.f;
}

__device__ __forceinline__ void gload16(const void* g, void* l) {
  __builtin_amdgcn_global_load_lds(
      (const __attribute__((address_space(1))) void*)g,
      (__attribute__((address_space(3))) void*)l, 16, 0, 0);
}

// ---------------- elementwise ----------------
__global__ void cast_bf16_kernel(const float* __restrict__ in, u16* __restrict__ out,
                                 u16* __restrict__ zpad) {
  int i = (blockIdx.x * 256 + threadIdx.x) * 4;
  fx4 v = *(const fx4*)(in + i);
  u16x4 o;
  #pragma unroll
  for (int j = 0; j < 4; ++j) o[j] = f2b(v[j]);
  *(u16x4*)(out + i) = o;
  if (blockIdx.x == 0) { zpad[threadIdx.x] = 0; zpad[threadIdx.x + 256] = 0; }
}

__global__ void avg3_kernel(const u16* __restrict__ o3, u16* __restrict__ out) {
  int i = (blockIdx.x * 256 + threadIdx.x) * 4;
  u16x4 a = *(const u16x4*)(o3 + i);
  u16x4 b = *(const u16x4*)(o3 + (size_t)Mm*Dm + i);
  u16x4 c = *(const u16x4*)(o3 + (size_t)2*Mm*Dm + i);
  u16x4 r;
  #pragma unroll
  for (int j = 0; j < 4; ++j)
    r[j] = f2b((b2f(a[j]) + b2f(b[j]) + b2f(c[j])) * (1.f/3.f));
  *(u16x4*)(out + i) = r;
}

// ---------------- layernorm (1 wave / row) ----------------
__global__ void ln_kernel(const float* __restrict__ in, const float* __restrict__ gam,
                          const float* __restrict__ bet, float* __restrict__ outf,
                          u16* __restrict__ outb) {
  int row = blockIdx.x;
  int t = threadIdx.x;  // 64
  const float* x = in + (size_t)row * Dm;
  fx4 v0 = *(const fx4*)(x + t*4);
  fx4 v1 = *(const fx4*)(x + 256 + t*4);
  float s = 0.f, sq = 0.f;
  #pragma unroll
  for (int j = 0; j < 4; ++j) { s += v0[j] + v1[j]; sq += v0[j]*v0[j] + v1[j]*v1[j]; }
  #pragma unroll
  for (int off = 1; off < 64; off <<= 1) { s += __shfl_xor(s, off, 64); sq += __shfl_xor(sq, off, 64); }
  float mu  = s * (1.f/Dm);
  float var = sq * (1.f/Dm) - mu*mu;
  float rstd = rsqrtf(var + 1e-6f);
  fx4 g0 = *(const fx4*)(gam + t*4), g1 = *(const fx4*)(gam + 256 + t*4);
  fx4 b0 = *(const fx4*)(bet + t*4), b1 = *(const fx4*)(bet + 256 + t*4);
  float* of = outf + (size_t)row*Dm;
  u16*   ob = outb + (size_t)row*Dm;
  fx4 y0, y1; u16x4 h0, h1;
  #pragma unroll
  for (int j = 0; j < 4; ++j) {
    y0[j] = (v0[j]-mu)*rstd*g0[j] + b0[j];
    y1[j] = (v1[j]-mu)*rstd*g1[j] + b1[j];
    h0[j] = f2b(y0[j]); h1[j] = f2b(y1[j]);
  }
  *(fx4*)(of + t*4) = y0; *(fx4*)(of + 256 + t*4) = y1;
  *(u16x4*)(ob + t*4) = h0; *(u16x4*)(ob + 256 + t*4) = h1;
}

// ---------------- weight prep: fp32 [K][N] -> bf16 pre-swizzled 128x64 LDS-tile images ----
// tile layout: for chunk z in [0,1024): row=z>>3 (n), cz=z&7; content = W[k0+(cz^(row&7))*8 .. +8][n0+row]
__global__ void prep_kernel(u16* __restrict__ packed,
    const float* __restrict__ Wq1, const float* __restrict__ Wq3, const float* __restrict__ Wq5,
    const float* __restrict__ Wk1, const float* __restrict__ Wk3, const float* __restrict__ Wk5,
    const float* __restrict__ Wv,  const float* __restrict__ Wo,
    const float* __restrict__ W1,  const float* __restrict__ W2, int layer) {
  constexpr int t0[13] = {0,32,128,288,320,416,576,608,640,672,704,832,960};
  int bid = blockIdx.x;
  int seg = 0;
  while (bid >= t0[seg+1]) ++seg;
  int local = bid - t0[seg];
  const float* src; int K, N;
  switch (seg) {
    case 0:  src = Wq1 + (size_t)layer*512*512;   K = 512;  N = 512;  break;
    case 1:  src = Wq3 + (size_t)layer*3*512*512; K = 1536; N = 512;  break;
    case 2:  src = Wq5 + (size_t)layer*5*512*512; K = 2560; N = 512;  break;
    case 3:  src = Wk1 + (size_t)layer*512*512;   K = 512;  N = 512;  break;
    case 4:  src = Wk3 + (size_t)layer*3*512*512; K = 1536; N = 512;  break;
    case 5:  src = Wk5 + (size_t)layer*5*512*512; K = 2560; N = 512;  break;
    case 6:  src = Wv + (size_t)(layer*3+0)*512*512; K = 512; N = 512; break;
    case 7:  src = Wv + (size_t)(layer*3+1)*512*512; K = 512; N = 512; break;
    case 8:  src = Wv + (size_t)(layer*3+2)*512*512; K = 512; N = 512; break;
    case 9:  src = Wo + (size_t)layer*512*512;    K = 512;  N = 512;  break;
    case 10: src = W1 + (size_t)layer*512*2048;   K = 512;  N = 2048; break;
    default: src = W2 + (size_t)layer*2048*512;   K = 2048; N = 512;  break;
  }
  int KT = K >> 6;
  int ntile = local / KT, ktile = local - ntile*KT;
  const float* sb = src + (size_t)(ktile*64)*N + ntile*128;
  u16* dst = packed + ((size_t)bid << 13);
  int tid = threadIdx.x;
  #pragma unroll
  for (int j = 0; j < 4; ++j) {
    int z = j*256 + tid;
    int row = z >> 3;
    int c = (z & 7) ^ (row & 7);
    const float* p = sb + (size_t)(c*8)*N + row;
    s16x8 o;
    #pragma unroll
    for (int e = 0; e < 8; ++e) o[e] = (short)f2b(p[(size_t)e*N]);
    *(s16x8*)(dst + z*8) = o;
  }
}

// ---------------- unified GEMM core (BK=64, global_load_lds, XOR-swizzled LDS) ----------
// MODE 0: bf16 out = acc+bias; MODE 1: bf16 out = relu(acc+bias); MODE 2: f32 out = acc+bias+res
template<int MODE, int BMt, int WN, bool CAUSAL>
__device__ __forceinline__ void gemm_core(const u16* __restrict__ A, int lda, int Ktap, int taps,
    const u16* __restrict__ Wt, const float* __restrict__ bias, const float* __restrict__ res,
    u16* __restrict__ outb, float* __restrict__ outf, int N, const u16* __restrict__ zpad) {
  constexpr int NR = 128 / (16 * WN);
  __shared__ __align__(16) u16 As[BMt * 64];
  __shared__ __align__(16) u16 Bs[8192];
  int tid = threadIdx.x, lane = tid & 63, wid = tid >> 6;
  int wm = (WN == 2) ? (wid >> 1) : 0;
  int wn = (WN == 2) ? (wid & 1) : wid;
  int r16 = lane & 15, g = lane >> 4;
  int brow = blockIdx.x * BMt, bcol = blockIdx.y * 128;
  int KT = Ktap >> 6;
  const u16* WtN = Wt + ((size_t)(blockIdx.y * taps * KT) << 13);
  fx4 acc[4][NR] = {};
  for (int t = 0; t < taps; ++t) {
    int shift = taps - 1 - t;
    for (int kt = 0; kt < KT; ++kt) {
      int c0 = kt << 6;
      #pragma unroll
      for (int j = 0; j < BMt/32; ++j) {       // A tile: BMt x 64 bf16
        int zb = wid*(BMt*2) + j*64;
        int zz = zb + lane;
        int row = zz >> 3;
        int c = (zz & 7) ^ (row & 7);
        int grow = brow + row;
        const u16* src;
        if (CAUSAL) {
          int s = grow & (Sm - 1);
          src = (s >= shift) ? (A + (size_t)(grow - shift)*lda + c0 + c*8) : zpad;
        } else {
          src = A + (size_t)grow*lda + c0 + c*8;
        }
        gload16(src, &As[zb * 8]);
      }
      const u16* wt = WtN + ((size_t)(t*KT + kt) << 13);
      #pragma unroll
      for (int j = 0; j < 4; ++j) {            // B tile: linear copy (pre-swizzled)
        int zb = wid*256 + j*64;
        gload16(wt + (size_t)(zb + lane)*8, &Bs[zb * 8]);
      }
      __syncthreads();
      bf16x8 a[2][4], b[2][NR];
      #pragma unroll
      for (int kk = 0; kk < 2; ++kk) {
        #pragma unroll
        for (int m = 0; m < 4; ++m) {
          int row = wm*64 + m*16 + r16;
          a[kk][m] = *(const bf16x8*)(&As[(row << 6) + (((kk*4 + g) ^ (row & 7)) << 3)]);
        }
        #pragma unroll
        for (int n = 0; n < NR; ++n) {
          int row = wn*(NR*16) + n*16 + r16;
          b[kk][n] = *(const bf16x8*)(&Bs[(row << 6) + (((kk*4 + g) ^ (row & 7)) << 3)]);
        }
      }
      #pragma unroll
      for (int kk = 0; kk < 2; ++kk)
        #pragma unroll
        for (int m = 0; m < 4; ++m)
          #pragma unroll
          for (int n = 0; n < NR; ++n)
            acc[m][n] = __builtin_amdgcn_mfma_f32_16x16x32_bf16(a[kk][m], b[kk][n], acc[m][n], 0, 0, 0);
      __syncthreads();
    }
  }
  #pragma unroll
  for (int m = 0; m < 4; ++m) {
    int row0 = brow + wm*64 + m*16 + g*4;
    #pragma unroll
    for (int n = 0; n < NR; ++n) {
      int col = bcol + wn*(NR*16) + n*16 + r16;
      float bv_ = bias[col];
      #pragma unroll
      for (int r = 0; r < 4; ++r) {
        size_t idx = (size_t)(row0 + r)*N + col;
        float v = acc[m][n][r] + bv_;
        if (MODE == 0)      outb[idx] = f2b(v);
        else if (MODE == 1) outb[idx] = f2b(fmaxf(v, 0.f));
        else                outf[idx] = v + res[idx];
      }
    }
  }
}

// conv wrapper: grid (32, 4, 9); z decodes q/k/v x branch
__global__ __launch_bounds__(256, 2) void gemm_conv(const u16* __restrict__ xb,
    const u16* __restrict__ packed,
    const float* __restrict__ bq, const float* __restrict__ bk, const float* __restrict__ bv,
    u16* __restrict__ qb, u16* __restrict__ kb, u16* __restrict__ vb, int layer,
    const u16* __restrict__ zpad) {
  constexpr int t0[9] = {0,32,128,288,320,416,576,608,640};
  int z = blockIdx.z;
  int which = z / 3, br = z - which*3;
  int taps = (which == 2) ? 1 : ((br == 0) ? 1 : (br == 1) ? 3 : 5);
  const u16* Wt = packed + ((size_t)t0[z] << 13);
  const float* bias = ((which == 0) ? bq : (which == 1) ? bk : bv) + (size_t)(layer*3 + br)*Dm;
  u16* out = ((which == 0) ? qb : (which == 1) ? kb : vb) + (size_t)br*(size_t)Mm*Dm;
  gemm_core<0, 128, 2, true>(xb, 512, 512, taps, Wt, bias, nullptr, out, nullptr, 512, zpad);
}

template<int MODE, int BMt, int WN>
__global__ __launch_bounds__(256, 2) void gemm_dense(const u16* __restrict__ A, int lda, int K,
    const u16* __restrict__ Wt, const float* __restrict__ bias, const float* __restrict__ res,
    u16* __restrict__ outb, float* __restrict__ outf, int N) {
  gemm_core<MODE, BMt, WN, false>(A, lda, K, 1, Wt, bias, res, outb, outf, N, nullptr);
}

// ---------------- flash attention: grid (qtile 8, b*h 64, branch 3), 256 thr ----------------
__global__ void attn_kernel(const u16* __restrict__ qb, const u16* __restrict__ kb,
                            const u16* __restrict__ vb, u16* __restrict__ ob) {
  __shared__ u16 Ks[64][72];
  __shared__ u16 Vs[64][72];        // transposed: Vs[d][k]
  __shared__ u16 Ps[4][16][72];     // per-wave P tile
  int qt = blockIdx.x, bh = blockIdx.y, br = blockIdx.z;
  int b = bh >> 3, h = bh & 7;
  const u16* q = qb + (size_t)br*Mm*Dm;
  const u16* k = kb + (size_t)br*Mm*Dm;
  const u16* v = vb + (size_t)br*Mm*Dm;
  u16* o = ob + (size_t)br*Mm*Dm;
  int tid = threadIdx.x, lane = tid & 63, wid = tid >> 6;
  int r16 = lane & 15, g = lane >> 4;
  size_t rowbase = (size_t)b * Sm;
  int qrow0 = qt*64 + wid*16;

  bf16x8 qa[2];
  #pragma unroll
  for (int c = 0; c < 2; ++c)
    qa[c] = *(const bf16x8*)(q + (rowbase + qrow0 + r16)*Dm + h*64 + c*32 + g*8);

  float mrow[4], lrow[4];
  fx4 accO[4] = {};
  #pragma unroll
  for (int r = 0; r < 4; ++r) { mrow[r] = -3.0e38f; lrow[r] = 0.f; }

  for (int kt = 0; kt <= qt; ++kt) {
    #pragma unroll
    for (int it = 0; it < 2; ++it) {
      int idx = it*256 + tid;
      int row = idx >> 3, ch = (idx & 7) * 8;
      s16x8 kv = *(const s16x8*)(k + (rowbase + kt*64 + row)*Dm + h*64 + ch);
      *(s16x8*)(&Ks[row][ch]) = kv;
      s16x8 vv = *(const s16x8*)(v + (rowbase + kt*64 + row)*Dm + h*64 + ch);
      #pragma unroll
      for (int j = 0; j < 8; ++j) Vs[ch+j][row] = (u16)vv[j];
    }
    __syncthreads();
    fx4 sacc[4] = {};
    #pragma unroll
    for (int n = 0; n < 4; ++n)
      #pragma unroll
      for (int c = 0; c < 2; ++c) {
        bf16x8 kf = *(const bf16x8*)(&Ks[n*16 + r16][c*32 + g*8]);
        sacc[n] = __builtin_amdgcn_mfma_f32_16x16x32_bf16(qa[c], kf, sacc[n], 0, 0, 0);
      }
    float sv[4][4];
    bool diag = (kt == qt);
    #pragma unroll
    for (int n = 0; n < 4; ++n)
      #pragma unroll
      for (int r = 0; r < 4; ++r) {
        float s = sacc[n][r] * 0.125f;
        if (diag) {
          int col = n*16 + r16;
          int rowq = wid*16 + g*4 + r;
          if (col > rowq) s = -3.0e38f;
        }
        sv[n][r] = s;
      }
    #pragma unroll
    for (int r = 0; r < 4; ++r) {
      float rm = fmaxf(fmaxf(sv[0][r], sv[1][r]), fmaxf(sv[2][r], sv[3][r]));
      #pragma unroll
      for (int off = 1; off < 16; off <<= 1) rm = fmaxf(rm, __shfl_xor(rm, off, 64));
      float mnew = fmaxf(mrow[r], rm);
      float corr = __expf(mrow[r] - mnew);
      mrow[r] = mnew;
      float rs = 0.f;
      #pragma unroll
      for (int n = 0; n < 4; ++n) { float p = __expf(sv[n][r] - mnew); sv[n][r] = p; rs += p; }
      #pragma unroll
      for (int off = 1; off < 16; off <<= 1) rs += __shfl_xor(rs, off, 64);
      lrow[r] = lrow[r]*corr + rs;
      #pragma unroll
      for (int n = 0; n < 4; ++n) accO[n][r] *= corr;
    }
    #pragma unroll
    for (int n = 0; n < 4; ++n)
      #pragma unroll
      for (int r = 0; r < 4; ++r)
        Ps[wid][g*4 + r][n*16 + r16] = f2b(sv[n][r]);
    #pragma unroll
    for (int kk = 0; kk < 2; ++kk) {
      bf16x8 pa = *(const bf16x8*)(&Ps[wid][r16][kk*32 + g*8]);
      #pragma unroll
      for (int n = 0; n < 4; ++n) {
        bf16x8 vf = *(const bf16x8*)(&Vs[n*16 + r16][kk*32 + g*8]);
        accO[n] = __builtin_amdgcn_mfma_f32_16x16x32_bf16(pa, vf, accO[n], 0, 0, 0);
      }
    }
    __syncthreads();
  }
  #pragma unroll
  for (int n = 0; n < 4; ++n)
    #pragma unroll
    for (int r = 0; r < 4; ++r) {
      int qrow = qt*64 + wid*16 + g*4 + r;
      o[(rowbase + qrow)*Dm + h*64 + n*16 + r16] = f2b(accO[n][r] / lrow[r]);
    }
}

// ---------------- host ----------------
extern "C" void kernel_launch(void* const* d_in, const int* in_sizes, int n_in,
                              void* d_out, int out_size, void* d_ws, size_t ws_size,
                              hipStream_t stream) {
  const float* x_in = (const float*)d_in[0];
  const float* Wq1 = (const float*)d_in[1];
  const float* Wk1 = (const float*)d_in[2];
  const float* Wq3 = (const float*)d_in[3];
  const float* Wk3 = (const float*)d_in[4];
  const float* Wq5 = (const float*)d_in[5];
  const float* Wk5 = (const float*)d_in[6];
  const float* bq  = (const float*)d_in[7];
  const float* bk  = (const float*)d_in[8];
  const float* Wv  = (const float*)d_in[9];
  const float* bv  = (const float*)d_in[10];
  const float* Wo  = (const float*)d_in[11];
  const float* bo  = (const float*)d_in[12];
  const float* W1  = (const float*)d_in[13];
  const float* b1  = (const float*)d_in[14];
  const float* W2  = (const float*)d_in[15];
  const float* b2  = (const float*)d_in[16];
  const float* ln1g = (const float*)d_in[17];
  const float* ln1b = (const float*)d_in[18];
  const float* ln2g = (const float*)d_in[19];
  const float* ln2b = (const float*)d_in[20];

  char* ws = (char*)d_ws;
  size_t off = 0;
  auto alloc = [&](size_t bytes) { void* p = ws + off; off += (bytes + 255) & ~(size_t)255; return p; };
  float* x_f32 = (float*)alloc((size_t)Mm*Dm*4);
  u16*   xb    = (u16*)  alloc((size_t)Mm*Dm*2);
  u16*   qbuf  = (u16*)  alloc((size_t)3*Mm*Dm*2);
  u16*   kbuf  = (u16*)  alloc((size_t)3*Mm*Dm*2);
  u16*   vbuf  = (u16*)  alloc((size_t)3*Mm*Dm*2);
  u16*   obuf  = (u16*)  alloc((size_t)3*Mm*Dm*2);
  u16*   avgb  = (u16*)  alloc((size_t)Mm*Dm*2);
  float* pre   = (float*)alloc((size_t)Mm*Dm*4);
  float* out1f = (float*)alloc((size_t)Mm*Dm*4);
  u16*   out1b = (u16*)  alloc((size_t)Mm*Dm*2);
  u16*   midb  = (u16*)  alloc((size_t)Mm*Fm*2);
  u16*   packed= (u16*)  alloc((size_t)960*8192*2);
  u16*   zpad  = (u16*)  alloc(1024);

  cast_bf16_kernel<<<2048, 256, 0, stream>>>(x_in, xb, zpad);
  for (int l = 0; l < Lm; ++l) {
    const float* xs = (l == 0) ? x_in : x_f32;
    prep_kernel<<<960, 256, 0, stream>>>(packed, Wq1, Wq3, Wq5, Wk1, Wk3, Wk5,
                                         Wv, Wo, W1, W2, l);
    gemm_conv<<<dim3(32, 4, 9), 256, 0, stream>>>(
        xb, packed, bq, bk, bv, qbuf, kbuf, vbuf, l, zpad);
    attn_kernel<<<dim3(8, 64, 3), 256, 0, stream>>>(qbuf, kbuf, vbuf, obuf);
    avg3_kernel<<<2048, 256, 0, stream>>>(obuf, avgb);
    gemm_dense<2, 64, 4><<<dim3(64, 4), 256, 0, stream>>>(
        avgb, 512, 512, packed + ((size_t)672 << 13), bo + (size_t)l*Dm, xs, nullptr, pre, 512);
    ln_kernel<<<4096, 64, 0, stream>>>(pre, ln1g + (size_t)l*Dm, ln1b + (size_t)l*Dm, out1f, out1b);
    gemm_dense<1, 128, 2><<<dim3(32, 16), 256, 0, stream>>>(
        out1b, 512, 512, packed + ((size_t)704 << 13), b1 + (size_t)l*Fm, nullptr, midb, nullptr, 2048);
    gemm_dense<2, 64, 4><<<dim3(64, 4), 256, 0, stream>>>(
        midb, 2048, 2048, packed + ((size_t)832 << 13), b2 + (size_t)l*Dm, out1f, nullptr, pre, 512);
    float* lnout = (l == Lm-1) ? (float*)d_out : x_f32;
    ln_kernel<<<4096, 64, 0, stream>>>(pre, ln2g + (size_t)l*Dm, ln2b + (size_t)l*Dm, lnout, xb);
  }
}